// Round 1
// baseline (134.492 us; speedup 1.0000x reference)
//
#include <hip/hip_runtime.h>
#include <hip/hip_bf16.h>
#include <cstdint>
#include <cstddef>

#define A_DIM 128
#define T_DIM 2048
#define F_DIM 128
#define RBF_DIM 16
#define TTILE 32
#define NCHUNK 8

__device__ __forceinline__ float silu_f(float x) {
    return x / (1.0f + __expf(-x));
}

// grid (A/4, 3), block 512. h1/h2 MLP layers for 4 atoms, one output/thread/layer.
__global__ void mlp12_kernel(const float* __restrict__ feat0,
                             const float* __restrict__ w1, const float* __restrict__ b1,
                             const float* __restrict__ w2, const float* __restrict__ b2,
                             float* __restrict__ h2ws) {
    __shared__ float inv_s[4 * F_DIM];
    __shared__ float h_s[4 * F_DIM];
    const int i  = blockIdx.y;
    const int a0 = blockIdx.x * 4;
    const int tid = threadIdx.x;
    const int f  = tid & 127;
    const int la = tid >> 7;

    inv_s[tid] = feat0[(a0 + la) * F_DIM + f];  // feat0 is (A,F,1)
    __syncthreads();

    const float* w1i = w1 + (size_t)i * F_DIM * F_DIM;
    float x = b1[i * F_DIM + f];
    #pragma unroll 8
    for (int k = 0; k < F_DIM; ++k)
        x = fmaf(inv_s[la * F_DIM + k], w1i[k * F_DIM + f], x);
    h_s[tid] = silu_f(x);
    __syncthreads();

    const float* w2i = w2 + (size_t)i * F_DIM * F_DIM;
    float y = b2[i * F_DIM + f];
    #pragma unroll 8
    for (int k = 0; k < F_DIM; ++k)
        y = fmaf(h_s[la * F_DIM + k], w2i[k * F_DIM + f], y);
    h2ws[((size_t)i * A_DIM + a0 + la) * F_DIM + f] = silu_f(y);
}

// grid (A/4, 2, 3), block 256. Layer 3: (4 atoms)x(1024 cols) tile, 4x4 register tile.
__global__ void mlp3_kernel(const float* __restrict__ h2ws,
                            const float* __restrict__ w3, const float* __restrict__ b3,
                            float* __restrict__ rbfws) {
    __shared__ float h2_s[4 * F_DIM];
    const int i  = blockIdx.z;
    const int a0 = blockIdx.x * 4;
    const int c0 = blockIdx.y * 1024;
    const int tid = threadIdx.x;

    for (int j = tid; j < 4 * F_DIM; j += 256)
        h2_s[j] = h2ws[((size_t)i * A_DIM + a0) * F_DIM + j];
    __syncthreads();

    const int c = c0 + tid * 4;
    const float* w3i = w3 + (size_t)i * F_DIM * 2048;
    float val[4][4];
    #pragma unroll
    for (int a = 0; a < 4; ++a) {
        #pragma unroll
        for (int cc = 0; cc < 4; ++cc)
            val[a][cc] = b3[i * 2048 + c + cc];
    }
    for (int k = 0; k < F_DIM; ++k) {
        const float4 w = *reinterpret_cast<const float4*>(&w3i[(size_t)k * 2048 + c]);
        #pragma unroll
        for (int a = 0; a < 4; ++a) {
            const float h = h2_s[a * F_DIM + k];
            val[a][0] = fmaf(h, w.x, val[a][0]);
            val[a][1] = fmaf(h, w.y, val[a][1]);
            val[a][2] = fmaf(h, w.z, val[a][2]);
            val[a][3] = fmaf(h, w.w, val[a][3]);
        }
    }
    const float inv_rbf = 0.25f;  // 1/sqrt(16)
    #pragma unroll
    for (int a = 0; a < 4; ++a) {
        float4 o;
        o.x = val[a][0] * inv_rbf;
        o.y = val[a][1] * inv_rbf;
        o.z = val[a][2] * inv_rbf;
        o.w = val[a][3] * inv_rbf;
        *reinterpret_cast<float4*>(&rbfws[((size_t)i * A_DIM + a0 + a) * 2048 + c]) = o;
    }
}

// grid (T/32, A/8), block 128 (thread = one f). Factorized einsum, acc into sparse (T,F).
__global__ void __launch_bounds__(128) contract_kernel(
        const float* __restrict__ feat0, const float* __restrict__ feat1,
        const float* __restrict__ feat2,
        const float* __restrict__ sph0,  const float* __restrict__ sph1,
        const float* __restrict__ sph2,
        const float* __restrict__ radial, const float* __restrict__ rbfws,
        float* __restrict__ sparse) {
    __shared__ float radial_s[TTILE * 16];
    __shared__ float sph_s[TTILE * 12];  // [t][0]=sph0, [1..3]=sph1, [4..8]=sph2 (stride 12 for 16B align)

    const int f  = threadIdx.x;
    const int t0 = blockIdx.x * TTILE;
    const int n0 = blockIdx.y * NCHUNK;

    float acc[TTILE];
    #pragma unroll
    for (int t = 0; t < TTILE; ++t) acc[t] = 0.0f;

    for (int nn = 0; nn < NCHUNK; ++nn) {
        const int n = n0 + nn;
        // stage radial[n, t0:t0+32, :] (512 contiguous floats)
        {
            const float4* rsrc = reinterpret_cast<const float4*>(radial + ((size_t)n * T_DIM + t0) * 16);
            reinterpret_cast<float4*>(radial_s)[f] = rsrc[f];
        }
        // stage sph: sph0 32 floats, sph1 96, sph2 160
        if (f < 32) sph_s[f * 12 + 0] = sph0[(size_t)n * T_DIM + t0 + f];
        if (f >= 32) {
            const int j = f - 32;  // 0..95
            sph_s[(j / 3) * 12 + 1 + (j % 3)] = sph1[((size_t)n * T_DIM + t0) * 3 + j];
        }
        for (int j = f; j < 160; j += 128)
            sph_s[(j / 5) * 12 + 4 + (j % 5)] = sph2[((size_t)n * T_DIM + t0) * 5 + j];
        __syncthreads();

        // per-thread invariants for this n (registers)
        float rb0[16], rb1[16], rb2[16];
        const float* rwsn = rbfws + (size_t)n * 2048 + f;
        #pragma unroll
        for (int r = 0; r < 16; ++r) {
            rb0[r] = rwsn[r * 128];
            rb1[r] = rwsn[262144 + r * 128];
            rb2[r] = rwsn[524288 + r * 128];
        }
        const float f0c = feat0[(size_t)n * F_DIM + f];
        float f1c[3], f2c[5];
        #pragma unroll
        for (int d = 0; d < 3; ++d) f1c[d] = feat1[((size_t)n * F_DIM + f) * 3 + d];
        #pragma unroll
        for (int d = 0; d < 5; ++d) f2c[d] = feat2[((size_t)n * F_DIM + f) * 5 + d];

        #pragma unroll 4
        for (int t = 0; t < TTILE; ++t) {
            float R0 = 0.0f, R1 = 0.0f, R2 = 0.0f;
            #pragma unroll
            for (int r = 0; r < 16; ++r) {
                const float rv = radial_s[t * 16 + r];
                R0 = fmaf(rv, rb0[r], R0);
                R1 = fmaf(rv, rb1[r], R1);
                R2 = fmaf(rv, rb2[r], R2);
            }
            const float* sp = &sph_s[t * 12];
            const float S0 = sp[0] * f0c;
            const float S1 = fmaf(sp[1], f1c[0], fmaf(sp[2], f1c[1], sp[3] * f1c[2]));
            const float S2 = fmaf(sp[4], f2c[0], fmaf(sp[5], f2c[1],
                             fmaf(sp[6], f2c[2], fmaf(sp[7], f2c[3], sp[8] * f2c[4]))));
            acc[t] = fmaf(S0, R0, fmaf(S1, R1, fmaf(S2, R2, acc[t])));
        }
        __syncthreads();
    }

    #pragma unroll
    for (int t = 0; t < TTILE; ++t)
        atomicAdd(&sparse[(size_t)(t0 + t) * F_DIM + f], acc[t]);
}

// grid (T/2), block 256: scatter sparse rows into d_out (duplicates via atomics).
__global__ void scatter_kernel(const float* __restrict__ sparse,
                               const int* __restrict__ tidx,
                               float* __restrict__ out) {
    const int tid = threadIdx.x;
    const int t = blockIdx.x * 2 + (tid >> 7);
    const int f = tid & 127;
    const int g = tidx[t];
    atomicAdd(&out[(size_t)g * F_DIM + f], sparse[(size_t)t * F_DIM + f]);
}

extern "C" void kernel_launch(void* const* d_in, const int* in_sizes, int n_in,
                              void* d_out, int out_size, void* d_ws, size_t ws_size,
                              hipStream_t stream) {
    const float* feat0  = (const float*)d_in[0];
    const float* feat1  = (const float*)d_in[1];
    const float* feat2  = (const float*)d_in[2];
    const float* sph0   = (const float*)d_in[3];
    const float* sph1   = (const float*)d_in[4];
    const float* sph2   = (const float*)d_in[5];
    const float* radial = (const float*)d_in[6];
    const float* w1     = (const float*)d_in[7];
    const float* b1     = (const float*)d_in[8];
    const float* w2     = (const float*)d_in[9];
    const float* b2     = (const float*)d_in[10];
    const float* w3     = (const float*)d_in[11];
    const float* b3     = (const float*)d_in[12];
    const int*   tidx   = (const int*)d_in[13];
    float* out = (float*)d_out;

    // workspace: rbf2f (3*128*16*128 f32 = 3 MB) | h2 (3*128*128) | sparse (T*F = 1 MB)
    float* rbfws  = (float*)d_ws;
    float* h2ws   = rbfws + 3 * A_DIM * RBF_DIM * F_DIM;
    float* sparse = h2ws + 3 * A_DIM * F_DIM;

    hipMemsetAsync(d_out, 0, (size_t)out_size * sizeof(float), stream);
    hipMemsetAsync(sparse, 0, (size_t)T_DIM * F_DIM * sizeof(float), stream);

    mlp12_kernel<<<dim3(A_DIM / 4, 3), 512, 0, stream>>>(feat0, w1, b1, w2, b2, h2ws);
    mlp3_kernel<<<dim3(A_DIM / 4, 2, 3), 256, 0, stream>>>(h2ws, w3, b3, rbfws);
    contract_kernel<<<dim3(T_DIM / TTILE, A_DIM / NCHUNK), 128, 0, stream>>>(
        feat0, feat1, feat2, sph0, sph1, sph2, radial, rbfws, sparse);
    scatter_kernel<<<dim3(T_DIM / 2), 256, 0, stream>>>(sparse, tidx, out);
}